// Round 1
// baseline (68.448 us; speedup 1.0000x reference)
//
#include <hip/hip_runtime.h>
#include <math.h>

// Problem constants (from reference): DT=1, V_LAMBDA=1e-4, V_RIDGE=1e-4
#define LAM3  1e-4f   // V_LAMBDA / DT^6
#define RIDGE 1e-4f
#define NN    64      // N
#define NP    65      // N+1

// (D3^T D3) band values for Np=65 (D3 is the [62,65] third-difference op).
// Interior stencil: diag 20, off1 -15, off2 6, off3 -1; boundaries truncated.
__device__ __forceinline__ float d3_diag(int f) {
    if (f == 0 || f == 64) return 1.f;
    if (f == 1 || f == 63) return 10.f;
    if (f == 2 || f == 62) return 19.f;
    return 20.f;
}
__device__ __forceinline__ float d3_off1(int f) { // [f][f-1], valid f>=1
    if (f == 1 || f == 64) return -3.f;
    if (f == 2 || f == 63) return -12.f;
    return -15.f;
}
__device__ __forceinline__ float d3_off2(int f) { // [f][f-2], valid f>=2
    if (f == 2 || f == 64) return 3.f;
    return 6.f;
}
// [f][f-3] == -1 everywhere it exists (f>=3)

__global__ __launch_bounds__(64) void alpamayo_banded_solve(
    const float* __restrict__ dxy,    // [B,64,2]
    const float* __restrict__ theta,  // [B,65]
    const float* __restrict__ v0,     // [B]
    float* __restrict__ out,          // [B,65]
    int B)
{
    // L-band records per row per thread: (L1, L2, L3, 1/diag)
    __shared__ float4 Lrec[NN][64];   // 64 KiB

    const int tid = threadIdx.x;
    const int b = blockIdx.x * 64 + tid;
    if (b >= B) return;

    const float* th = theta + (long)b * NP;
    const float* dx = dxy   + (long)b * (2 * NN);
    const float v0b = v0[b];

    float z[NN];  // forward-substitution result, fully unrolled -> registers

    // Streaming state
    float sp, cp;                    // sin/cos of theta[f-1]
    __sincosf(th[0], &sp, &cp);
    float bxp = 2.f * dx[0];         // b_x[f-1]
    float byp = 2.f * dx[1];         // b_y[f-1]

    // Rolling Cholesky state (rows i-1, i-2, i-3); zero-init implements the
    // boundary truncation automatically (couplings to full-index 0 and
    // nonexistent rows are multiplied by rd==0).
    float p1L1 = 0.f, p1L2 = 0.f, p2L1 = 0.f;
    float rd1 = 0.f, rd2 = 0.f, rd3 = 0.f;
    float z1 = 0.f, z2 = 0.f, z3 = 0.f;

    // Fused: sincos -> ATA band + rhs assembly -> banded Cholesky row ->
    // forward substitution.  Row i of the reduced NxN system == full index f=i+1.
    #pragma unroll
    for (int i = 0; i < NN; ++i) {
        const int f = i + 1;
        float sf, cf;
        __sincosf(th[f], &sf, &cf);
        const float e = cp * cf + sp * sf;       // ATA[f-1][f] = cos(dtheta)

        float bxc = 0.f, byc = 0.f;
        if (f < NN) { bxc = 2.f * dx[2 * f]; byc = 2.f * dx[2 * f + 1]; }
        float rhs = cf * (bxp + bxc) + sf * (byp + byc);

        // v0 corrections (couplings of rows 1..3 to full index 0)
        if (i == 0) rhs -= (e + LAM3 * -3.f) * v0b;
        if (i == 1) rhs -= (LAM3 *  3.f) * v0b;
        if (i == 2) rhs -= (LAM3 * -1.f) * v0b;

        // lhs band entries for row i (full index f)
        const float a0 = (f == NN ? 1.f : 2.f) + LAM3 * d3_diag(f) + RIDGE;
        const float a1 = e + LAM3 * d3_off1(f);    // killed by rd1=0 at i=0
        const float a2 = LAM3 * d3_off2(f);        // killed by rd2=0 at i<2
        const float a3 = LAM3 * -1.f;              // killed by rd3=0 at i<3

        // Banded Cholesky row
        const float Li3 = a3 * rd3;
        const float Li2 = (a2 - Li3 * p2L1) * rd2;
        const float Li1 = (a1 - Li3 * p1L2 - Li2 * p1L1) * rd1;
        const float dg  = a0 - Li3 * Li3 - Li2 * Li2 - Li1 * Li1;
        const float d   = sqrtf(dg);
        const float rd0 = 1.f / d;

        // Forward substitution
        const float zi = (rhs - Li3 * z3 - Li2 * z2 - Li1 * z1) * rd0;

        Lrec[i][tid] = make_float4(Li1, Li2, Li3, rd0);
        z[i] = zi;

        // Roll state
        p2L1 = p1L1; p1L1 = Li1; p1L2 = Li2;
        rd3 = rd2; rd2 = rd1; rd1 = rd0;
        z3 = z2; z2 = z1; z1 = zi;
        cp = cf; sp = sf; bxp = bxc; byp = byc;
    }

    // Back substitution: y_i = (z_i - L1[i+1]*y_{i+1} - L2[i+2]*y_{i+2}
    //                                - L3[i+3]*y_{i+3}) / d_i
    float r1L1 = 0.f, r1L2 = 0.f, r1L3 = 0.f;  // record of row i+1
    float r2L2 = 0.f, r2L3 = 0.f;              // record of row i+2
    float r3L3 = 0.f;                          // record of row i+3
    float y1 = 0.f, y2 = 0.f, y3 = 0.f;

    float* outp = out + (long)b * NP;

    #pragma unroll
    for (int i = NN - 1; i >= 0; --i) {
        const float4 rec = Lrec[i][tid];
        const float yi = (z[i] - r1L1 * y1 - r2L2 * y2 - r3L3 * y3) * rec.w;
        outp[1 + i] = yi;
        // roll records toward smaller i
        r3L3 = r2L3; r2L3 = r1L3; r2L2 = r1L2;
        r1L1 = rec.x; r1L2 = rec.y; r1L3 = rec.z;
        y3 = y2; y2 = y1; y1 = yi;
    }
    outp[0] = v0b;
}

extern "C" void kernel_launch(void* const* d_in, const int* in_sizes, int n_in,
                              void* d_out, int out_size, void* d_ws, size_t ws_size,
                              hipStream_t stream) {
    const float* dxy   = (const float*)d_in[0];   // [B,64,2]
    const float* theta = (const float*)d_in[1];   // [B,65]
    const float* v0    = (const float*)d_in[2];   // [B]
    float* out = (float*)d_out;                   // [B,65]
    const int B = in_sizes[2];
    const int blocks = (B + 63) / 64;
    alpamayo_banded_solve<<<blocks, 64, 0, stream>>>(dxy, theta, v0, out, B);
}

// Round 2
// 64.474 us; speedup vs baseline: 1.0616x; 1.0616x over previous
//
#include <hip/hip_runtime.h>
#include <math.h>

// Problem constants (from reference): DT=1, V_LAMBDA=1e-4, V_RIDGE=1e-4
#define LAM3  1e-4f   // V_LAMBDA / DT^6
#define RIDGE 1e-4f
#define NN    64      // N
#define NP    65      // N+1

// (D3^T D3) band values for Np=65 (third-difference smoother), boundary-truncated.
__device__ __forceinline__ float d3_diag(int f) {
    if (f == 0 || f == 64) return 1.f;
    if (f == 1 || f == 63) return 10.f;
    if (f == 2 || f == 62) return 19.f;
    return 20.f;
}
__device__ __forceinline__ float d3_off1(int f) { // [f][f-1], valid f>=1
    if (f == 1 || f == 64) return -3.f;
    if (f == 2 || f == 63) return -12.f;
    return -15.f;
}
__device__ __forceinline__ float d3_off2(int f) { // [f][f-2], valid f>=2
    if (f == 2 || f == 64) return 3.f;
    return 6.f;
}
// [f][f-3] == -1 everywhere it exists (f>=3)

__global__ __launch_bounds__(64, 1) void alpamayo_banded_solve(
    const float* __restrict__ dxy,    // [B,64,2]
    const float* __restrict__ theta,  // [B,65]
    const float* __restrict__ v0,     // [B]
    float* __restrict__ out,          // [B,65]
    int B)
{
    // Per-thread column layout: no cross-thread sharing -> no barriers needed.
    __shared__ float4 Lrec[NN][64];   // 64 KiB

    const int tid = threadIdx.x;
    const int b = blockIdx.x * 64 + tid;
    if (b >= B) return;

    const float* th = theta + (long)b * NP;
    // dxy row stride = 512 B -> always 16B-aligned; theta row stride 260 B -> scalar loads.
    const float4* dx4 = (const float4*)(dxy + (long)b * (2 * NN));
    const float v0b = v0[b];

    // ---- Preload ALL inputs into registers (puts ~100 loads in flight once) ----
    float thr[NP];
    #pragma unroll
    for (int f = 0; f < NP; ++f) thr[f] = th[f];
    float dxf[2 * NN];
    #pragma unroll
    for (int j = 0; j < 32; ++j) {
        const float4 q = dx4[j];
        dxf[4 * j + 0] = q.x; dxf[4 * j + 1] = q.y;
        dxf[4 * j + 2] = q.z; dxf[4 * j + 3] = q.w;
    }

    // ---- All transcendentals up front (independent, throughput-bound) ----
    float c[NP], s[NP];
    #pragma unroll
    for (int f = 0; f < NP; ++f) __sincosf(thr[f], &s[f], &c[f]);

    // ---- rhs and off-diagonal e (independent per row) ----
    float rhs[NN], e[NN];
    #pragma unroll
    for (int i = 0; i < NN; ++i) {
        const int f = i + 1;
        const float bx = dxf[2 * f - 2] + (f < NN ? dxf[2 * f] : 0.f);
        const float by = dxf[2 * f - 1] + (f < NN ? dxf[2 * f + 1] : 0.f);
        rhs[i] = 2.f * (c[f] * bx + s[f] * by);
        e[i] = c[i] * c[f] + s[i] * s[f];   // = cos(theta_f - theta_{f-1})
    }
    // v0 corrections (couplings of reduced rows 0..2 to full index 0)
    rhs[0] -= (e[0] + LAM3 * -3.f) * v0b;
    rhs[1] -= (LAM3 *  3.f) * v0b;
    rhs[2] -= (LAM3 * -1.f) * v0b;

    // ---- Fused banded Cholesky + forward substitution (the serial chain) ----
    float z[NN];
    float p1L1 = 0.f, p1L2 = 0.f, p2L1 = 0.f;
    float rd1 = 0.f, rd2 = 0.f, rd3 = 0.f;
    float z1 = 0.f, z2 = 0.f, z3 = 0.f;

    #pragma unroll
    for (int i = 0; i < NN; ++i) {
        const int f = i + 1;
        const float a0 = (f == NN ? 1.f : 2.f) + LAM3 * d3_diag(f) + RIDGE;
        const float a1 = e[i] + LAM3 * d3_off1(f);   // killed by rd1=0 at i=0
        const float a2 = LAM3 * d3_off2(f);          // killed by rd2=0 at i<2
        const float a3 = LAM3 * -1.f;                // killed by rd3=0 at i<3

        const float Li3 = a3 * rd3;
        const float Li2 = (a2 - Li3 * p2L1) * rd2;
        const float Li1 = (a1 - Li3 * p1L2 - Li2 * p1L1) * rd1;
        const float dg  = a0 - Li3 * Li3 - Li2 * Li2 - Li1 * Li1;
        const float rd0 = __builtin_amdgcn_rsqf(dg);   // single v_rsq_f32 (was sqrt+IEEE div)

        const float zi = (rhs[i] - Li3 * z3 - Li2 * z2 - Li1 * z1) * rd0;

        Lrec[i][tid] = make_float4(Li1, Li2, Li3, rd0);
        z[i] = zi;

        p2L1 = p1L1; p1L1 = Li1; p1L2 = Li2;
        rd3 = rd2; rd2 = rd1; rd1 = rd0;
        z3 = z2; z2 = z1; z1 = zi;
    }

    // ---- Back substitution ----
    float r1L1 = 0.f, r1L2 = 0.f, r1L3 = 0.f;
    float r2L2 = 0.f, r2L3 = 0.f;
    float r3L3 = 0.f;
    float y1 = 0.f, y2 = 0.f, y3 = 0.f;

    float* outp = out + (long)b * NP;

    #pragma unroll
    for (int i = NN - 1; i >= 0; --i) {
        const float4 rec = Lrec[i][tid];
        const float yi = (z[i] - r1L1 * y1 - r2L2 * y2 - r3L3 * y3) * rec.w;
        outp[1 + i] = yi;
        r3L3 = r2L3; r2L3 = r1L3; r2L2 = r1L2;
        r1L1 = rec.x; r1L2 = rec.y; r1L3 = rec.z;
        y3 = y2; y2 = y1; y1 = yi;
    }
    outp[0] = v0b;
}

extern "C" void kernel_launch(void* const* d_in, const int* in_sizes, int n_in,
                              void* d_out, int out_size, void* d_ws, size_t ws_size,
                              hipStream_t stream) {
    const float* dxy   = (const float*)d_in[0];   // [B,64,2]
    const float* theta = (const float*)d_in[1];   // [B,65]
    const float* v0    = (const float*)d_in[2];   // [B]
    float* out = (float*)d_out;                   // [B,65]
    const int B = in_sizes[2];
    const int blocks = (B + 63) / 64;
    alpamayo_banded_solve<<<blocks, 64, 0, stream>>>(dxy, theta, v0, out, B);
}